// Round 2
// baseline (921.561 us; speedup 1.0000x reference)
//
#include <hip/hip_runtime.h>
#include <hip/hip_bf16.h>

// WindowAttention: B=2048 windows, N=98 tokens, C=192, H=6 heads, hd=32, nw=64 masks.
// K0 prep (x->f16 into d_out scratch, o_w/qkv_w->f16, merged (bias+mask)*log2e table bm);
// K1 QKV GEMM: 64x64... actually 64x64? -> 64-row x 64-col tiles, async global_load_lds
//   staging with XOR source-swizzle; V third written TRANSPOSED [b][h][d][i] to global.
// K2 attention: swapped QK^T (mfma(K,Q)) so each lane owns a full q-row; softmax fully
//   in-register (2 shuffles/reduce); P (only LDS) written b64, read back by the SAME wave
//   -> ZERO barriers; V fragments read direct from transposed global layout.
// K3 out-proj (32x32 tile/wave, XCD swizzle) unchanged.
// d_out scratch: xh f16 (77,070,336 B @0) + bm f32 (19,267,584 B @77,070,336); K3 overwrites.

#define NB   2048
#define NN   98
#define CC   192
#define NH   6
#define HD   32
#define NWIN 64
#define MM   (NB * NN)          // 200704 rows
#define HEADBLK (NN * HD)       // 3136 elements per (b,s,h) slice

typedef _Float16 half8  __attribute__((ext_vector_type(8)));
typedef _Float16 half4  __attribute__((ext_vector_type(4)));
typedef float    f32x4  __attribute__((ext_vector_type(4)));

// 16B vector with only 4B alignment (V^T rows have stride 196B)
struct __attribute__((packed, aligned(4))) half8u { half8 v; };

__device__ __forceinline__ f32x4 mfma16(half8 a, half8 b, f32x4 c) {
    return __builtin_amdgcn_mfma_f32_16x16x32_f16(a, b, c, 0, 0, 0);
}

typedef __attribute__((address_space(3))) unsigned int       lds_uint;
typedef __attribute__((address_space(1))) const unsigned int g_uint;
__device__ __forceinline__ void async_copy16(void* lds, const void* g) {
    __builtin_amdgcn_global_load_lds((g_uint*)g, (lds_uint*)lds, 16, 0, 0);
}

// ---------------- workspace layout (bytes) ----------------
// qkv f16   : [2048][3][6][...]               231,211,008 B @ 0
//   (Q,K thirds: [98][32] per (b,s,h); V third TRANSPOSED: [32][98] per (b,h))
// attn_out  : [200704][192] f16                77,070,336 B @ 231,211,008
//   (first 221,184 B alias the f16 qkv_w copy: K0 writes, K1 reads, K2 overwrites)
// o_w f16   : [192][192]                           73,728 B @ 308,281,344
#define WS_QKV   0ull
#define WS_AO    231211008ull
#define WS_W2    308281344ull
#define XH_BYTES 77070336ull    // xh f16 in d_out @0; bm f32 in d_out @XH_BYTES

// ---------------- K0: prep ----------------
__global__ __launch_bounds__(256) void wa_k0_prep(
    const float* __restrict__ x,
    const float* __restrict__ o_w, const float* __restrict__ qkv_w,
    const float* __restrict__ bias_table, const int* __restrict__ rel_index,
    const float* __restrict__ mask,
    _Float16* __restrict__ w2, _Float16* __restrict__ wqh,
    float* __restrict__ bm, _Float16* __restrict__ xh)
{
    int t = blockIdx.x * 256 + threadIdx.x;
    if (t < CC * CC) {
        w2[t] = (_Float16)o_w[t];
    } else if (t < 4 * CC * CC) {
        int e = t - CC * CC;
        wqh[e] = (_Float16)qkv_w[e];
    }
    const size_t stride = (size_t)gridDim.x * 256;
    // bulk x (f32) -> xh (f16): 4,816,896 granules of 8
    const size_t total_g = (size_t)MM * CC / 8;
    for (size_t g = t; g < total_g; g += stride) {
        const float* s = x + g * 8;
        float4 v0 = *(const float4*)s;
        float4 v1 = *(const float4*)(s + 4);
        half8 hv = { (_Float16)v0.x, (_Float16)v0.y, (_Float16)v0.z, (_Float16)v0.w,
                     (_Float16)v1.x, (_Float16)v1.y, (_Float16)v1.z, (_Float16)v1.w };
        *(half8*)(xh + g * 8) = hv;
    }
    // merged (bias+mask)*log2e table: bm[w][h][i][128], cols >= 98 = -1e30
    const size_t bm_total = (size_t)NWIN * NH * NN * 128;   // 4,816,896
    for (size_t e = t; e < bm_total; e += stride) {
        int j   = (int)(e & 127);
        int row = (int)(e >> 7);        // (w*6+h)*98 + i
        int i   = row % NN;
        int wh  = row / NN;
        int hh  = wh % NH;
        int ww  = wh / NH;
        float v = -1.0e30f;
        if (j < NN)
            v = (bias_table[rel_index[i * NN + j] * NH + hh]
               + mask[((size_t)ww * NN + i) * NN + j]) * 1.4426950408889634f;
        bm[e] = v;
    }
}

// ---------------- K1: QKV projection GEMM ----------------
// 64x64 output tile; A staged async into linear LDS [64][192] with XOR source-swizzle;
// B direct from f16 qkv_w copy. V third written transposed [d][i]. Grid 28224, XCD swizzle.
__global__ __launch_bounds__(256) void wa_k1_qkv(
    const _Float16* __restrict__ xh, const _Float16* __restrict__ wqh,
    const float* __restrict__ qkv_b, _Float16* __restrict__ qkv)
{
    const int id = blockIdx.x;                 // 0..28223 = 8*9*392
    const int c8 = id & 7;
    const int nb = (id >> 3) % 9;              // 0..8
    const int mb = (id / 72) * 8 + c8;         // 0..3135
    __shared__ __align__(128) _Float16 As[64 * 192];   // 24 KB, linear rows of 384 B

    const int tid  = threadIdx.x;
    const int lane = tid & 63, wave = tid >> 6;

    // async stage: 24 KB = 6 rounds x 4 waves x 64 lanes x 16 B, XOR swizzle on source
    {
        const char* xb = (const char*)(xh + (size_t)mb * 64 * CC);
        char* lb = (char*)As + wave * 1024;
        #pragma unroll
        for (int i = 0; i < 6; ++i) {
            int off = i * 4096 + wave * 1024 + lane * 16;
            int row = off / 384;
            int col = off - row * 384;
            int src = row * 384 + (col ^ ((row & 7) << 4));
            async_copy16(lb + i * 4096, xb + src);
        }
    }

    const int l16 = lane & 15, quad = lane >> 4;
    const _Float16* bbase = wqh + (size_t)(nb * 64 + l16) * CC + quad * 8;

    half8 b0[4];
    #pragma unroll
    for (int nt = 0; nt < 4; ++nt) b0[nt] = *(const half8*)(bbase + nt * 16 * CC);

    __syncthreads();

    const char* asb = (const char*)As;
    const int sx = (l16 & 7) << 4;
    const int r0 = (wave * 16 + l16) * 384;
    const int cb = quad * 16;

    f32x4 acc[4] = {};
    #pragma unroll
    for (int kk = 0; kk < 6; ++kk) {
        int c = (cb + kk * 64) ^ sx;
        half8 a0 = *(const half8*)(asb + r0 + c);
        #pragma unroll
        for (int nt = 0; nt < 4; ++nt) {
            half8 b = (kk == 0) ? b0[nt]
                                : *(const half8*)(bbase + nt * 16 * CC + kk * 32);
            acc[nt] = mfma16(a0, b, acc[nt]);
        }
    }

    // epilogue: + qkv_b, scatter f16; V third (s==2) transposed [d][i]
    const int s = nb / 3;                      // uniform per block
    int bArr[4], iArr[4];
    #pragma unroll
    for (int r = 0; r < 4; ++r) {
        int m = mb * 64 + wave * 16 + quad * 4 + r;
        int b_ = m / NN;
        bArr[r] = b_;
        iArr[r] = m - b_ * NN;
    }
    #pragma unroll
    for (int nt = 0; nt < 4; ++nt) {
        int j = nb * 64 + nt * 16 + l16;        // 0..575
        float bias = qkv_b[j];
        int rm = j - s * CC;
        int h  = rm >> 5;
        int d  = rm & 31;
        #pragma unroll
        for (int r = 0; r < 4; ++r) {
            _Float16 val = (_Float16)(acc[nt][r] + bias);
            if (s == 2)
                qkv[((size_t)(bArr[r] * 3 + 2) * NH + h) * HEADBLK + d * NN + iArr[r]] = val;
            else
                qkv[((size_t)(bArr[r] * 3 + s) * NH + h) * HEADBLK + iArr[r] * HD + d] = val;
        }
    }
}

// ---------------- K2: attention, swapped QK^T, zero barriers ----------------
// 448 threads = 7 waves; wave = q-tile (16 rows). Lane owns one q-row:
// S^T = mfma(K_frag, Q_frag) -> lane (l16,quad) holds keys {16jt+4quad+r} of row wave*16+l16.
__global__ __launch_bounds__(448, 6) void wa_k2_attn(
    const _Float16* __restrict__ qkv, const float* __restrict__ bm,
    _Float16* __restrict__ ao)
{
    const int h = blockIdx.x;           // 0..5
    const int b = blockIdx.y;           // 0..2047
    const int w = b & (NWIN - 1);
    const _Float16* qp = qkv + ((size_t)(b * 3 + 0) * NH + h) * HEADBLK;
    const _Float16* kp = qkv + ((size_t)(b * 3 + 1) * NH + h) * HEADBLK;
    const _Float16* vt = qkv + ((size_t)(b * 3 + 2) * NH + h) * HEADBLK;  // [d][i]

    __shared__ __align__(16) _Float16 P[112 * 136];   // unnormalized probs, wave-private rows

    const int tid  = threadIdx.x;
    const int lane = tid & 63, wave = tid >> 6;
    const int l16  = lane & 15, quad = lane >> 4;

    const int qrow = wave * 16 + l16;               // 0..111
    const int qrc  = qrow < NN ? qrow : NN - 1;     // clamp pad rows

    const float scale2 = 0.17677669529663687f * 1.4426950408889634f;  // hd^-0.5 * log2e

    half8 bq = *(const half8*)(qp + qrc * HD + quad * 8);             // Q as B-operand
    const float* bmrow = bm + ((size_t)(w * NH + h) * NN + qrc) * 128;

    // S^T: 7 key tiles; garbage keys >= 98 killed by bm = -1e30
    f32x4 s[7];
    #pragma unroll
    for (int jt = 0; jt < 7; ++jt) {
        half8 ak = *(const half8*)(kp + (jt * 16 + l16) * HD + quad * 8);
        f32x4 z = {};
        s[jt] = mfma16(ak, bq, z);
    }
    #pragma unroll
    for (int jt = 0; jt < 7; ++jt) {
        float4 bmv = *(const float4*)(bmrow + jt * 16 + quad * 4);
        s[jt][0] = fmaf(s[jt][0], scale2, bmv.x);
        s[jt][1] = fmaf(s[jt][1], scale2, bmv.y);
        s[jt][2] = fmaf(s[jt][2], scale2, bmv.z);
        s[jt][3] = fmaf(s[jt][3], scale2, bmv.w);
    }

    // row max: vector tree over 7 tiles, horizontal, 2 cross-quad shuffles
    f32x4 vm = s[0];
    #pragma unroll
    for (int jt = 1; jt < 7; ++jt) {
        vm[0] = fmaxf(vm[0], s[jt][0]); vm[1] = fmaxf(vm[1], s[jt][1]);
        vm[2] = fmaxf(vm[2], s[jt][2]); vm[3] = fmaxf(vm[3], s[jt][3]);
    }
    float mx = fmaxf(fmaxf(vm[0], vm[1]), fmaxf(vm[2], vm[3]));
    mx = fmaxf(mx, __shfl_xor(mx, 16));
    mx = fmaxf(mx, __shfl_xor(mx, 32));

    // exp2, vector-tree sum, 2 shuffles
    f32x4 vs = {};
    #pragma unroll
    for (int jt = 0; jt < 7; ++jt) {
        #pragma unroll
        for (int r = 0; r < 4; ++r) {
            float p = __builtin_amdgcn_exp2f(s[jt][r] - mx);
            s[jt][r] = p;
            vs[r] += p;
        }
    }
    float sum = (vs[0] + vs[1]) + (vs[2] + vs[3]);
    sum += __shfl_xor(sum, 16);
    sum += __shfl_xor(sum, 32);
    float inv = __builtin_amdgcn_rcpf(sum);

    // write unnormalized P (own rows only): 7 packed b64 + zero-fill cols 112..127
    _Float16* prow = P + qrow * 136;
    #pragma unroll
    for (int jt = 0; jt < 7; ++jt) {
        half4 hv = { (_Float16)s[jt][0], (_Float16)s[jt][1],
                     (_Float16)s[jt][2], (_Float16)s[jt][3] };
        *(half4*)(prow + jt * 16 + quad * 4) = hv;
    }
    { half4 z4 = {}; *(half4*)(prow + 112 + quad * 4) = z4; }

    // per-output-row 1/sum via intra-wave shuffle (source lane quad*4+r holds that row)
    float invr[4];
    #pragma unroll
    for (int r = 0; r < 4; ++r) invr[r] = __shfl(inv, quad * 4 + r);

    // PV: A = own P rows (same-wave LDS, in-order -> no barrier), B = V^T direct global
    half8 pa[4];
    #pragma unroll
    for (int kc = 0; kc < 4; ++kc)
        pa[kc] = *(const half8*)(P + qrow * 136 + kc * 32 + quad * 8);

    #pragma unroll
    for (int nt = 0; nt < 2; ++nt) {
        f32x4 acc = {};
        #pragma unroll
        for (int kc = 0; kc < 4; ++kc) {
            half8 vb = ((const half8u*)(vt + (nt * 16 + l16) * NN + kc * 32 + quad * 8))->v;
            acc = mfma16(pa[kc], vb, acc);
        }
        #pragma unroll
        for (int r = 0; r < 4; ++r) {
            int i = wave * 16 + quad * 4 + r;
            if (i < NN)
                ao[((size_t)b * NN + i) * CC + h * HD + nt * 16 + l16] =
                    (_Float16)(acc[r] * invr[r]);
        }
    }
}

// ---------------- K3: output projection, 32x32 tile per wave ----------------
__global__ __launch_bounds__(256) void wa_k3_proj(
    const _Float16* __restrict__ ao, const _Float16* __restrict__ w2,
    const float* __restrict__ o_b, float* __restrict__ out)
{
    const int id = blockIdx.x;                 // 0..9407 = 8*6*196
    const int c8 = id & 7;
    const int nt = (id >> 3) % 6;
    const int msuper = (id / 48) * 8 + c8;     // 0..1567
    const int lane = threadIdx.x & 63, wave = threadIdx.x >> 6;
    const int l16 = lane & 15, quad = lane >> 4;

    const int m0 = msuper * 128 + wave * 32;
    const int e0 = nt * 32;
    const _Float16* ap = ao + (size_t)(m0 + l16) * CC + quad * 8;
    const _Float16* bp = w2 + (size_t)(e0 + l16) * CC + quad * 8;

    f32x4 acc[2][2] = {};
    #pragma unroll
    for (int kk = 0; kk < 6; ++kk) {
        half8 a0 = *(const half8*)(ap + kk * 32);
        half8 a1 = *(const half8*)(ap + 16 * CC + kk * 32);
        half8 b0 = *(const half8*)(bp + kk * 32);
        half8 b1 = *(const half8*)(bp + 16 * CC + kk * 32);
        acc[0][0] = mfma16(a0, b0, acc[0][0]);
        acc[0][1] = mfma16(a0, b1, acc[0][1]);
        acc[1][0] = mfma16(a1, b0, acc[1][0]);
        acc[1][1] = mfma16(a1, b1, acc[1][1]);
    }
    #pragma unroll
    for (int ni = 0; ni < 2; ++ni) {
        int e = e0 + ni * 16 + l16;
        float ob = o_b[e];
        #pragma unroll
        for (int mi = 0; mi < 2; ++mi)
            #pragma unroll
            for (int r = 0; r < 4; ++r) {
                int m = m0 + mi * 16 + quad * 4 + r;
                out[(size_t)m * CC + e] = acc[mi][ni][r] + ob;
            }
    }
}

// ---------------- launcher ----------------
extern "C" void kernel_launch(void* const* d_in, const int* in_sizes, int n_in,
                              void* d_out, int out_size, void* d_ws, size_t ws_size,
                              hipStream_t stream)
{
    const float* x          = (const float*)d_in[0];
    const float* mask       = (const float*)d_in[1];
    const float* qkv_w      = (const float*)d_in[2];
    const float* qkv_b      = (const float*)d_in[3];
    const float* o_w        = (const float*)d_in[4];
    const float* o_b        = (const float*)d_in[5];
    const float* bias_table = (const float*)d_in[6];
    const int*   rel_index  = (const int*)d_in[7];

    char* ws = (char*)d_ws;
    _Float16* qkv = (_Float16*)(ws + WS_QKV);
    _Float16* ao  = (_Float16*)(ws + WS_AO);
    _Float16* wqh = (_Float16*)(ws + WS_AO);    // alias: consumed by K1 before K2 writes ao
    _Float16* w2  = (_Float16*)(ws + WS_W2);
    float*    out = (float*)d_out;
    _Float16* xh  = (_Float16*)d_out;                       // K0 writes, K1 reads
    float*    bm  = (float*)((char*)d_out + XH_BYTES);      // K0 writes, K2 reads; K3 overwrites

    wa_k0_prep<<<2048, 256, 0, stream>>>(
        x, o_w, qkv_w, bias_table, rel_index, mask, w2, wqh, bm, xh);
    wa_k1_qkv<<<28224, 256, 0, stream>>>(xh, wqh, qkv_b, qkv);
    wa_k2_attn<<<dim3(NH, NB), 448, 0, stream>>>(qkv, bm, ao);
    wa_k3_proj<<<9408, 256, 0, stream>>>(ao, w2, o_b, out);
}

// Round 4
// 703.381 us; speedup vs baseline: 1.3102x; 1.3102x over previous
//
#include <hip/hip_runtime.h>
#include <hip/hip_bf16.h>

// WindowAttention: B=2048 windows, N=98 tokens, C=192, H=6 heads, hd=32, nw=64 masks.
// K0 prep (x->f16 into d_out scratch, o_w/qkv_w->f16, merged (bias+mask)*log2e table bm);
// K1 QKV GEMM: PERSISTENT 2-phase pipeline. Block = fixed 64-col strip x 4 consecutive
//   64-row tiles; B + bias in registers; A double-buffered in LDS via async global_load_lds
//   (XOR source-swizzle); counted s_waitcnt vmcnt(6) + raw s_barrier; last iter vmcnt(0),
//   no trailing stage (avoids dangling LDS-DMA at endpgm). Tile stride = 24576 B (64x384B).
//   V third written TRANSPOSED [b][h][d][i].
// K2 attention: swapped QK^T (mfma(K,Q)), softmax in-register, P wave-private LDS, zero
//   barriers, V^T direct global.
// K3 out-proj: same persistent 2-phase template as K1 (A = ao, B = w2, f32 output).
// d_out scratch: xh f16 (77,070,336 B @0) + bm f32 (19,267,584 B @77,070,336); K3 overwrites.

#define NB   2048
#define NN   98
#define CC   192
#define NH   6
#define HD   32
#define NWIN 64
#define MM   (NB * NN)          // 200704 rows
#define HEADBLK (NN * HD)       // 3136 elements per (b,s,h) slice
#define TILE_BYTES 24576        // 64 rows x 192 f16 cols x 2 B

typedef _Float16 half8  __attribute__((ext_vector_type(8)));
typedef _Float16 half4  __attribute__((ext_vector_type(4)));
typedef float    f32x4  __attribute__((ext_vector_type(4)));

// 16B vector with only 4B alignment (V^T rows have stride 196B)
struct __attribute__((packed, aligned(4))) half8u { half8 v; };

__device__ __forceinline__ f32x4 mfma16(half8 a, half8 b, f32x4 c) {
    return __builtin_amdgcn_mfma_f32_16x16x32_f16(a, b, c, 0, 0, 0);
}

typedef __attribute__((address_space(3))) unsigned int       lds_uint;
typedef __attribute__((address_space(1))) const unsigned int g_uint;
__device__ __forceinline__ void async_copy16(void* lds, const void* g) {
    __builtin_amdgcn_global_load_lds((g_uint*)g, (lds_uint*)lds, 16, 0, 0);
}

// ---------------- workspace layout (bytes) ----------------
// qkv f16   : [2048][3][6][...]               231,211,008 B @ 0
//   (Q,K thirds: [98][32] per (b,s,h); V third TRANSPOSED: [32][98] per (b,h))
// attn_out  : [200704][192] f16                77,070,336 B @ 231,211,008
//   (first 221,184 B alias the f16 qkv_w copy: K0 writes, K1 reads, K2 overwrites)
// o_w f16   : [192][192]                           73,728 B @ 308,281,344
#define WS_QKV   0ull
#define WS_AO    231211008ull
#define WS_W2    308281344ull
#define XH_BYTES 77070336ull    // xh f16 in d_out @0; bm f32 in d_out @XH_BYTES

// ---------------- K0: prep ----------------
__global__ __launch_bounds__(256) void wa_k0_prep(
    const float* __restrict__ x,
    const float* __restrict__ o_w, const float* __restrict__ qkv_w,
    const float* __restrict__ bias_table, const int* __restrict__ rel_index,
    const float* __restrict__ mask,
    _Float16* __restrict__ w2, _Float16* __restrict__ wqh,
    float* __restrict__ bm, _Float16* __restrict__ xh)
{
    int t = blockIdx.x * 256 + threadIdx.x;
    if (t < CC * CC) {
        w2[t] = (_Float16)o_w[t];
    } else if (t < 4 * CC * CC) {
        int e = t - CC * CC;
        wqh[e] = (_Float16)qkv_w[e];
    }
    const size_t stride = (size_t)gridDim.x * 256;
    // bulk x (f32) -> xh (f16): 4,816,896 granules of 8
    const size_t total_g = (size_t)MM * CC / 8;
    for (size_t g = t; g < total_g; g += stride) {
        const float* s = x + g * 8;
        float4 v0 = *(const float4*)s;
        float4 v1 = *(const float4*)(s + 4);
        half8 hv = { (_Float16)v0.x, (_Float16)v0.y, (_Float16)v0.z, (_Float16)v0.w,
                     (_Float16)v1.x, (_Float16)v1.y, (_Float16)v1.z, (_Float16)v1.w };
        *(half8*)(xh + g * 8) = hv;
    }
    // merged (bias+mask)*log2e table: bm[w][h][i][128], cols >= 98 = -1e30
    const size_t bm_total = (size_t)NWIN * NH * NN * 128;   // 4,816,896
    for (size_t e = t; e < bm_total; e += stride) {
        int j   = (int)(e & 127);
        int row = (int)(e >> 7);        // (w*6+h)*98 + i
        int i   = row % NN;
        int wh  = row / NN;
        int hh  = wh % NH;
        int ww  = wh / NH;
        float v = -1.0e30f;
        if (j < NN)
            v = (bias_table[rel_index[i * NN + j] * NH + hh]
               + mask[((size_t)ww * NN + i) * NN + j]) * 1.4426950408889634f;
        bm[e] = v;
    }
}

// ---------------- K1: QKV projection GEMM (persistent 2-phase) ----------------
// grid 7056 = 8 xcd * (9 nb * 98 chunks); chunk = 4 consecutive 64-row tiles.
// B (24 x half8) + bias in registers; A double-buffered 2x24KB LDS, async staged with
// XOR source-swizzle; counted vmcnt(6) keeps the prefetch in flight across barriers.
__global__ __launch_bounds__(256, 3) void wa_k1_qkv(
    const _Float16* __restrict__ xh, const _Float16* __restrict__ wqh,
    const float* __restrict__ qkv_b, _Float16* __restrict__ qkv)
{
    const int id = blockIdx.x;               // 0..7055
    const int c8 = id & 7;
    const int r  = id >> 3;                  // 0..881 = 9*98
    const int nb = r % 9;
    const int chunk = c8 * 98 + r / 9;       // 0..783
    __shared__ __align__(128) _Float16 As[2][64 * 192];   // 2 x 24 KB

    const int tid  = threadIdx.x;
    const int lane = tid & 63, wave = tid >> 6;
    const int l16  = lane & 15, quad = lane >> 4;

    // per-lane swizzled source offsets (constant across tiles)
    int soff[6];
    #pragma unroll
    for (int i = 0; i < 6; ++i) {
        int off = i * 4096 + wave * 1024 + lane * 16;
        int row = off / 384;
        int col = off - row * 384;
        soff[i] = row * 384 + (col ^ ((row & 7) << 4));
    }

    // B fragments in registers: 6 kk x 4 nt
    half8 breg[6][4];
    const _Float16* bbase = wqh + (size_t)(nb * 64 + l16) * CC + quad * 8;
    #pragma unroll
    for (int kk = 0; kk < 6; ++kk)
        #pragma unroll
        for (int nt = 0; nt < 4; ++nt)
            breg[kk][nt] = *(const half8*)(bbase + nt * 16 * CC + kk * 32);

    float bias[4];
    #pragma unroll
    for (int nt = 0; nt < 4; ++nt) bias[nt] = qkv_b[nb * 64 + nt * 16 + l16];

    // pin B/bias load issue before any staging (keeps "newest 6 = next tile" invariant)
    asm volatile("" ::: "memory");

    const int s = nb / 3;                    // 0=Q 1=K 2=V (uniform per block)
    const int mb0 = chunk * 4;

    // prologue: stage tile 0 into buf 0
    {
        const char* xb = (const char*)xh + (size_t)mb0 * TILE_BYTES;
        char* dst = (char*)As[0] + wave * 1024;
        #pragma unroll
        for (int i = 0; i < 6; ++i)
            async_copy16(dst + i * 4096, xb + soff[i]);
    }

    const int sx = (l16 & 7) << 4;
    const int rr = (wave * 16 + l16) * 384;
    const int cb = quad * 16;

    #pragma unroll
    for (int t = 0; t < 4; ++t) {
        // stage next tile (skip on last iteration)
        if (t < 3) {
            const char* xb = (const char*)xh + (size_t)(mb0 + t + 1) * TILE_BYTES;
            char* dst = (char*)As[(t + 1) & 1] + wave * 1024;
            #pragma unroll
            for (int i = 0; i < 6; ++i)
                async_copy16(dst + i * 4096, xb + soff[i]);
            asm volatile("s_waitcnt vmcnt(6)" ::: "memory");   // tile t landed; t+1 in flight
        } else {
            asm volatile("s_waitcnt vmcnt(0)" ::: "memory");   // final tile landed
        }
        __builtin_amdgcn_s_barrier();
        asm volatile("" ::: "memory");

        const char* asb = (const char*)As[t & 1];
        f32x4 acc[4] = {};
        #pragma unroll
        for (int kk = 0; kk < 6; ++kk) {
            half8 a0 = *(const half8*)(asb + rr + ((cb + kk * 64) ^ sx));
            #pragma unroll
            for (int nt = 0; nt < 4; ++nt)
                acc[nt] = mfma16(a0, breg[kk][nt], acc[nt]);
        }

        // epilogue tile t: + bias, scatter f16; V third transposed [d][i]
        const int mb = mb0 + t;
        int bArr[4], iArr[4];
        #pragma unroll
        for (int rq = 0; rq < 4; ++rq) {
            int m = mb * 64 + wave * 16 + quad * 4 + rq;
            int b_ = m / NN;
            bArr[rq] = b_;
            iArr[rq] = m - b_ * NN;
        }
        #pragma unroll
        for (int nt = 0; nt < 4; ++nt) {
            int j  = nb * 64 + nt * 16 + l16;
            int rm = j - s * CC;
            int hh = rm >> 5;
            int d  = rm & 31;
            #pragma unroll
            for (int rq = 0; rq < 4; ++rq) {
                _Float16 val = (_Float16)(acc[nt][rq] + bias[nt]);
                if (s == 2)
                    qkv[((size_t)(bArr[rq] * 3 + 2) * NH + hh) * HEADBLK + d * NN + iArr[rq]] = val;
                else
                    qkv[((size_t)(bArr[rq] * 3 + s) * NH + hh) * HEADBLK + iArr[rq] * HD + d] = val;
            }
        }
        asm volatile("" ::: "memory");
        __builtin_amdgcn_s_barrier();      // protect buf[t&1] before next-iter staging overwrites
        asm volatile("" ::: "memory");
    }
}

// ---------------- K2: attention, swapped QK^T, zero barriers ----------------
__global__ __launch_bounds__(448, 6) void wa_k2_attn(
    const _Float16* __restrict__ qkv, const float* __restrict__ bm,
    _Float16* __restrict__ ao)
{
    const int h = blockIdx.x;           // 0..5
    const int b = blockIdx.y;           // 0..2047
    const int w = b & (NWIN - 1);
    const _Float16* qp = qkv + ((size_t)(b * 3 + 0) * NH + h) * HEADBLK;
    const _Float16* kp = qkv + ((size_t)(b * 3 + 1) * NH + h) * HEADBLK;
    const _Float16* vt = qkv + ((size_t)(b * 3 + 2) * NH + h) * HEADBLK;  // [d][i]

    __shared__ __align__(16) _Float16 P[112 * 136];   // unnormalized probs, wave-private rows

    const int tid  = threadIdx.x;
    const int lane = tid & 63, wave = tid >> 6;
    const int l16  = lane & 15, quad = lane >> 4;

    const int qrow = wave * 16 + l16;               // 0..111
    const int qrc  = qrow < NN ? qrow : NN - 1;     // clamp pad rows

    const float scale2 = 0.17677669529663687f * 1.4426950408889634f;  // hd^-0.5 * log2e

    half8 bq = *(const half8*)(qp + qrc * HD + quad * 8);             // Q as B-operand
    const float* bmrow = bm + ((size_t)(w * NH + h) * NN + qrc) * 128;

    // S^T: 7 key tiles; garbage keys >= 98 killed by bm = -1e30
    f32x4 s[7];
    #pragma unroll
    for (int jt = 0; jt < 7; ++jt) {
        half8 ak = *(const half8*)(kp + (jt * 16 + l16) * HD + quad * 8);
        f32x4 z = {};
        s[jt] = mfma16(ak, bq, z);
    }
    #pragma unroll
    for (int jt = 0; jt < 7; ++jt) {
        float4 bmv = *(const float4*)(bmrow + jt * 16 + quad * 4);
        s[jt][0] = fmaf(s[jt][0], scale2, bmv.x);
        s[jt][1] = fmaf(s[jt][1], scale2, bmv.y);
        s[jt][2] = fmaf(s[jt][2], scale2, bmv.z);
        s[jt][3] = fmaf(s[jt][3], scale2, bmv.w);
    }

    // row max: vector tree, then 2 cross-half shuffles
    f32x4 vm = s[0];
    #pragma unroll
    for (int jt = 1; jt < 7; ++jt) {
        vm[0] = fmaxf(vm[0], s[jt][0]); vm[1] = fmaxf(vm[1], s[jt][1]);
        vm[2] = fmaxf(vm[2], s[jt][2]); vm[3] = fmaxf(vm[3], s[jt][3]);
    }
    float mx = fmaxf(fmaxf(vm[0], vm[1]), fmaxf(vm[2], vm[3]));
    mx = fmaxf(mx, __shfl_xor(mx, 16));
    mx = fmaxf(mx, __shfl_xor(mx, 32));

    // exp2, vector-tree sum, 2 shuffles
    f32x4 vs = {};
    #pragma unroll
    for (int jt = 0; jt < 7; ++jt) {
        #pragma unroll
        for (int rr = 0; rr < 4; ++rr) {
            float p = __builtin_amdgcn_exp2f(s[jt][rr] - mx);
            s[jt][rr] = p;
            vs[rr] += p;
        }
    }
    float sum = (vs[0] + vs[1]) + (vs[2] + vs[3]);
    sum += __shfl_xor(sum, 16);
    sum += __shfl_xor(sum, 32);
    float inv = __builtin_amdgcn_rcpf(sum);

    // write unnormalized P (own rows only): 7 packed b64 + zero-fill cols 112..127
    _Float16* prow = P + qrow * 136;
    #pragma unroll
    for (int jt = 0; jt < 7; ++jt) {
        half4 hv = { (_Float16)s[jt][0], (_Float16)s[jt][1],
                     (_Float16)s[jt][2], (_Float16)s[jt][3] };
        *(half4*)(prow + jt * 16 + quad * 4) = hv;
    }
    { half4 z4 = {}; *(half4*)(prow + 112 + quad * 4) = z4; }

    // per-output-row 1/sum via intra-wave shuffle
    float invr[4];
    #pragma unroll
    for (int rr = 0; rr < 4; ++rr) invr[rr] = __shfl(inv, quad * 4 + rr);

    // PV: A = own P rows (same-wave LDS, in-order), B = V^T direct global
    half8 pa[4];
    #pragma unroll
    for (int kc = 0; kc < 4; ++kc)
        pa[kc] = *(const half8*)(P + qrow * 136 + kc * 32 + quad * 8);

    #pragma unroll
    for (int nt = 0; nt < 2; ++nt) {
        f32x4 acc = {};
        #pragma unroll
        for (int kc = 0; kc < 4; ++kc) {
            half8 vb = ((const half8u*)(vt + (nt * 16 + l16) * NN + kc * 32 + quad * 8))->v;
            acc = mfma16(pa[kc], vb, acc);
        }
        #pragma unroll
        for (int rr = 0; rr < 4; ++rr) {
            int i = wave * 16 + quad * 4 + rr;
            if (i < NN)
                ao[((size_t)b * NN + i) * CC + h * HD + nt * 16 + l16] =
                    (_Float16)(acc[rr] * invr[rr]);
        }
    }
}

// ---------------- K3: output projection (persistent 2-phase, same template) ----------------
// grid 2352 = 8 xcd * (3 nb * 98 chunks); chunk = 4 consecutive 64-row tiles of ao.
__global__ __launch_bounds__(256, 3) void wa_k3_proj(
    const _Float16* __restrict__ ao, const _Float16* __restrict__ w2,
    const float* __restrict__ o_b, float* __restrict__ out)
{
    const int id = blockIdx.x;               // 0..2351
    const int c8 = id & 7;
    const int r  = id >> 3;                  // 0..293 = 3*98
    const int nb = r % 3;
    const int chunk = c8 * 98 + r / 3;       // 0..783
    __shared__ __align__(128) _Float16 As[2][64 * 192];   // 2 x 24 KB

    const int tid  = threadIdx.x;
    const int lane = tid & 63, wave = tid >> 6;
    const int l16  = lane & 15, quad = lane >> 4;

    int soff[6];
    #pragma unroll
    for (int i = 0; i < 6; ++i) {
        int off = i * 4096 + wave * 1024 + lane * 16;
        int row = off / 384;
        int col = off - row * 384;
        soff[i] = row * 384 + (col ^ ((row & 7) << 4));
    }

    half8 breg[6][4];
    const _Float16* bbase = w2 + (size_t)(nb * 64 + l16) * CC + quad * 8;
    #pragma unroll
    for (int kk = 0; kk < 6; ++kk)
        #pragma unroll
        for (int nt = 0; nt < 4; ++nt)
            breg[kk][nt] = *(const half8*)(bbase + nt * 16 * CC + kk * 32);

    float ob[4];
    #pragma unroll
    for (int nt = 0; nt < 4; ++nt) ob[nt] = o_b[nb * 64 + nt * 16 + l16];

    asm volatile("" ::: "memory");

    const int mb0 = chunk * 4;
    {
        const char* xb = (const char*)ao + (size_t)mb0 * TILE_BYTES;
        char* dst = (char*)As[0] + wave * 1024;
        #pragma unroll
        for (int i = 0; i < 6; ++i)
            async_copy16(dst + i * 4096, xb + soff[i]);
    }

    const int sx = (l16 & 7) << 4;
    const int rr = (wave * 16 + l16) * 384;
    const int cb = quad * 16;

    #pragma unroll
    for (int t = 0; t < 4; ++t) {
        if (t < 3) {
            const char* xb = (const char*)ao + (size_t)(mb0 + t + 1) * TILE_BYTES;
            char* dst = (char*)As[(t + 1) & 1] + wave * 1024;
            #pragma unroll
            for (int i = 0; i < 6; ++i)
                async_copy16(dst + i * 4096, xb + soff[i]);
            asm volatile("s_waitcnt vmcnt(6)" ::: "memory");
        } else {
            asm volatile("s_waitcnt vmcnt(0)" ::: "memory");
        }
        __builtin_amdgcn_s_barrier();
        asm volatile("" ::: "memory");

        const char* asb = (const char*)As[t & 1];
        f32x4 acc[4] = {};
        #pragma unroll
        for (int kk = 0; kk < 6; ++kk) {
            half8 a0 = *(const half8*)(asb + rr + ((cb + kk * 64) ^ sx));
            #pragma unroll
            for (int nt = 0; nt < 4; ++nt)
                acc[nt] = mfma16(a0, breg[kk][nt], acc[nt]);
        }

        const int mb = mb0 + t;
        #pragma unroll
        for (int nt = 0; nt < 4; ++nt) {
            int e = nb * 64 + nt * 16 + l16;
            #pragma unroll
            for (int rq = 0; rq < 4; ++rq) {
                int m = mb * 64 + wave * 16 + quad * 4 + rq;
                out[(size_t)m * CC + e] = acc[nt][rq] + ob[nt];
            }
        }
        asm volatile("" ::: "memory");
        __builtin_amdgcn_s_barrier();
        asm volatile("" ::: "memory");
    }
}

// ---------------- launcher ----------------
extern "C" void kernel_launch(void* const* d_in, const int* in_sizes, int n_in,
                              void* d_out, int out_size, void* d_ws, size_t ws_size,
                              hipStream_t stream)
{
    const float* x          = (const float*)d_in[0];
    const float* mask       = (const float*)d_in[1];
    const float* qkv_w      = (const float*)d_in[2];
    const float* qkv_b      = (const float*)d_in[3];
    const float* o_w        = (const float*)d_in[4];
    const float* o_b        = (const float*)d_in[5];
    const float* bias_table = (const float*)d_in[6];
    const int*   rel_index  = (const int*)d_in[7];

    char* ws = (char*)d_ws;
    _Float16* qkv = (_Float16*)(ws + WS_QKV);
    _Float16* ao  = (_Float16*)(ws + WS_AO);
    _Float16* wqh = (_Float16*)(ws + WS_AO);    // alias: consumed by K1 before K2 writes ao
    _Float16* w2  = (_Float16*)(ws + WS_W2);
    float*    out = (float*)d_out;
    _Float16* xh  = (_Float16*)d_out;                       // K0 writes, K1 reads
    float*    bm  = (float*)((char*)d_out + XH_BYTES);      // K0 writes, K2 reads; K3 overwrites

    wa_k0_prep<<<2048, 256, 0, stream>>>(
        x, o_w, qkv_w, bias_table, rel_index, mask, w2, wqh, bm, xh);
    wa_k1_qkv<<<7056, 256, 0, stream>>>(xh, wqh, qkv_b, qkv);
    wa_k2_attn<<<dim3(NH, NB), 448, 0, stream>>>(qkv, bm, ao);
    wa_k3_proj<<<2352, 256, 0, stream>>>(ao, w2, o_b, out);
}

// Round 5
// 681.613 us; speedup vs baseline: 1.3520x; 1.0319x over previous
//
#include <hip/hip_runtime.h>
#include <hip/hip_bf16.h>

// WindowAttention: B=2048 windows, N=98 tokens, C=192, H=6 heads, hd=32, nw=64 masks.
// K0 prep (x->f16 into d_out scratch, o_w/qkv_w->f16, merged (bias+mask)*log2e table bm);
// K1 QKV GEMM: persistent DEPTH-2 pipeline, 3 LDS buffers, chunk = 8 consecutive 64-row
//   tiles x fixed 64-col strip. Q/K tiles use operand-SWAPPED mfma (lane owns row m,
//   registers own 4 consecutive cols) -> 4 coalesced half4 stores/tile. V tiles use
//   unswapped mfma and store into a globally-transposed slab vtg[h][d][m] -> 4 half4
//   stores/tile. Uniform 4 stores/tile makes counted vmcnt exact: steady vmcnt(20).
// K2 attention: swapped QK^T, softmax in-register, P wave-private LDS, zero barriers,
//   V^T rows read direct from vtg.
// K3 out-proj: same depth-2 template (T=4), swapped mfma -> 4 float4 stores/tile.
// d_out scratch: xh f16 (77,070,336 B @0) + bm f32 (19,267,584 B @77,070,336); K3 overwrites.

#define NB   2048
#define NN   98
#define CC   192
#define NH   6
#define HD   32
#define NWIN 64
#define MM   (NB * NN)          // 200704 rows
#define HEADBLK (NN * HD)       // 3136 elements per (b,s,h) slice
#define TILE_BYTES 24576        // 64 rows x 192 f16 cols x 2 B

typedef _Float16 half8  __attribute__((ext_vector_type(8)));
typedef _Float16 half4  __attribute__((ext_vector_type(4)));
typedef float    f32x4  __attribute__((ext_vector_type(4)));

// 16B vector with only 4B alignment (V^T rows in vtg are 4B-aligned at b*98 offsets)
struct __attribute__((packed, aligned(4))) half8u { half8 v; };

__device__ __forceinline__ f32x4 mfma16(half8 a, half8 b, f32x4 c) {
    return __builtin_amdgcn_mfma_f32_16x16x32_f16(a, b, c, 0, 0, 0);
}

typedef __attribute__((address_space(3))) unsigned int       lds_uint;
typedef __attribute__((address_space(1))) const unsigned int g_uint;
__device__ __forceinline__ void async_copy16(void* lds, const void* g) {
    __builtin_amdgcn_global_load_lds((g_uint*)g, (lds_uint*)lds, 16, 0, 0);
}

// ---------------- workspace layout (bytes) ----------------
// qk  f16   : [2048][2][6][98][32]            154,140,672 B @ 0            (Q,K thirds)
// vtg f16   : [6][32][200704]                  77,070,336 B @ 154,140,672  (V transposed, m-major)
// attn_out  : [200704][192] f16                77,070,336 B @ 231,211,008
//   (first 221,184 B alias the f16 qkv_w copy: K0 writes, K1 reads, K2 overwrites)
// o_w f16   : [192][192]                           73,728 B @ 308,281,344
#define WS_QK    0ull
#define WS_VT    154140672ull
#define WS_AO    231211008ull
#define WS_W2    308281344ull
#define XH_BYTES 77070336ull    // xh f16 in d_out @0; bm f32 in d_out @XH_BYTES

// ---------------- K0: prep ----------------
__global__ __launch_bounds__(256) void wa_k0_prep(
    const float* __restrict__ x,
    const float* __restrict__ o_w, const float* __restrict__ qkv_w,
    const float* __restrict__ bias_table, const int* __restrict__ rel_index,
    const float* __restrict__ mask,
    _Float16* __restrict__ w2, _Float16* __restrict__ wqh,
    float* __restrict__ bm, _Float16* __restrict__ xh)
{
    int t = blockIdx.x * 256 + threadIdx.x;
    if (t < CC * CC) {
        w2[t] = (_Float16)o_w[t];
    } else if (t < 4 * CC * CC) {
        int e = t - CC * CC;
        wqh[e] = (_Float16)qkv_w[e];
    }
    const size_t stride = (size_t)gridDim.x * 256;
    // bulk x (f32) -> xh (f16): 4,816,896 granules of 8
    const size_t total_g = (size_t)MM * CC / 8;
    for (size_t g = t; g < total_g; g += stride) {
        const float* s = x + g * 8;
        float4 v0 = *(const float4*)s;
        float4 v1 = *(const float4*)(s + 4);
        half8 hv = { (_Float16)v0.x, (_Float16)v0.y, (_Float16)v0.z, (_Float16)v0.w,
                     (_Float16)v1.x, (_Float16)v1.y, (_Float16)v1.z, (_Float16)v1.w };
        *(half8*)(xh + g * 8) = hv;
    }
    // merged (bias+mask)*log2e table: bm[w][h][i][128], cols >= 98 = -1e30
    const size_t bm_total = (size_t)NWIN * NH * NN * 128;   // 4,816,896
    for (size_t e = t; e < bm_total; e += stride) {
        int j   = (int)(e & 127);
        int row = (int)(e >> 7);        // (w*6+h)*98 + i
        int i   = row % NN;
        int wh  = row / NN;
        int hh  = wh % NH;
        int ww  = wh / NH;
        float v = -1.0e30f;
        if (j < NN)
            v = (bias_table[rel_index[i * NN + j] * NH + hh]
               + mask[((size_t)ww * NN + i) * NN + j]) * 1.4426950408889634f;
        bm[e] = v;
    }
}

// ---------------- K1: QKV projection GEMM (persistent depth-2) ----------------
// grid 3528 = 8 xcd * 9 nb * 49; chunk = 8 consecutive 64-row tiles. B + bias in regs;
// A triple-buffered 3x24KB LDS, async staged with XOR source-swizzle; counted vmcnt
// keeps 2 tiles in flight (steady vmcnt(20) = 4 stores+6 loads+4 stores+6 loads trailing).
__global__ __launch_bounds__(256, 2) void wa_k1_qkv(
    const _Float16* __restrict__ xh, const _Float16* __restrict__ wqh,
    const float* __restrict__ qkv_b, _Float16* __restrict__ qk,
    _Float16* __restrict__ vtg)
{
    const int id = blockIdx.x;               // 0..3527
    const int c8 = id & 7;
    const int r  = id >> 3;                  // 0..440 = 9*49
    const int nb = r % 9;
    const int chunk = c8 * 49 + r / 9;       // 0..391
    __shared__ __align__(128) _Float16 As[3][64 * 192];   // 3 x 24 KB

    const int tid  = threadIdx.x;
    const int lane = tid & 63, wave = tid >> 6;
    const int l16  = lane & 15, quad = lane >> 4;

    // per-lane swizzled source offsets (constant across tiles)
    int soff[6];
    #pragma unroll
    for (int i = 0; i < 6; ++i) {
        int off = i * 4096 + wave * 1024 + lane * 16;
        int row = off / 384;
        int col = off - row * 384;
        soff[i] = row * 384 + (col ^ ((row & 7) << 4));
    }

    const int s   = nb / 3;                  // 0=Q 1=K 2=V (uniform per block)
    const int nbr = nb - s * 3;

    // B fragments in registers: 6 kk x 4 nt
    half8 breg[6][4];
    const _Float16* bbase = wqh + (size_t)(nb * 64 + l16) * CC + quad * 8;
    #pragma unroll
    for (int kk = 0; kk < 6; ++kk)
        #pragma unroll
        for (int nt = 0; nt < 4; ++nt)
            breg[kk][nt] = *(const half8*)(bbase + nt * 16 * CC + kk * 32);

    float4 biasq[4];     // swapped path (Q/K): 4 consecutive cols per (nt, quad)
    float  biasv[4];     // unswapped path (V): col j = nb*64+nt*16+l16
    if (s == 2) {
        #pragma unroll
        for (int nt = 0; nt < 4; ++nt) biasv[nt] = qkv_b[nb * 64 + nt * 16 + l16];
    } else {
        #pragma unroll
        for (int nt = 0; nt < 4; ++nt)
            biasq[nt] = *(const float4*)(qkv_b + nb * 64 + nt * 16 + quad * 4);
    }

    asm volatile("" ::: "memory");

    const char* xb0 = (const char*)xh + (size_t)chunk * 8 * TILE_BYTES;
    // prologue: stage tiles 0,1 into buf 0,1
    #pragma unroll
    for (int p = 0; p < 2; ++p) {
        char* dst = (char*)As[p] + wave * 1024;
        const char* src = xb0 + (size_t)p * TILE_BYTES;
        #pragma unroll
        for (int i = 0; i < 6; ++i)
            async_copy16(dst + i * 4096, src + soff[i]);
    }

    const int sx   = (l16 & 7) << 4;
    const int rowb = (wave * 16 + l16) * 384;
    const int cb   = quad * 16;

    #pragma unroll
    for (int t = 0; t < 8; ++t) {
        if (t < 6) {
            char* dst = (char*)As[(t + 2) % 3] + wave * 1024;
            const char* src = xb0 + (size_t)(t + 2) * TILE_BYTES;
            #pragma unroll
            for (int i = 0; i < 6; ++i)
                async_copy16(dst + i * 4096, src + soff[i]);
        }
        // counted waits: N = exact trailing op count after tile t's 6 loads
        if (t == 0)      asm volatile("s_waitcnt vmcnt(12)" ::: "memory");
        else if (t == 1) asm volatile("s_waitcnt vmcnt(16)" ::: "memory");
        else if (t < 6)  asm volatile("s_waitcnt vmcnt(20)" ::: "memory");
        else if (t == 6) asm volatile("s_waitcnt vmcnt(14)" ::: "memory");
        else             asm volatile("s_waitcnt vmcnt(8)"  ::: "memory");
        __builtin_amdgcn_s_barrier();
        asm volatile("" ::: "memory");

        const char* asb = (const char*)As[t % 3];
        const int mb = chunk * 8 + t;
        f32x4 acc[4] = {};

        if (s == 2) {
            // V: unswapped -> lane owns col j (h,d), registers own 4 consecutive m
            #pragma unroll
            for (int kk = 0; kk < 6; ++kk) {
                half8 a0 = *(const half8*)(asb + rowb + ((cb + kk * 64) ^ sx));
                #pragma unroll
                for (int nt = 0; nt < 4; ++nt)
                    acc[nt] = mfma16(a0, breg[kk][nt], acc[nt]);
            }
            const int m0v = mb * 64 + wave * 16 + quad * 4;
            #pragma unroll
            for (int nt = 0; nt < 4; ++nt) {
                int rm = nbr * 64 + nt * 16 + l16;
                int hh = rm >> 5, d = rm & 31;
                half4 hv = { (_Float16)(acc[nt][0] + biasv[nt]),
                             (_Float16)(acc[nt][1] + biasv[nt]),
                             (_Float16)(acc[nt][2] + biasv[nt]),
                             (_Float16)(acc[nt][3] + biasv[nt]) };
                *(half4*)(vtg + (size_t)(hh * 32 + d) * MM + m0v) = hv;
            }
        } else {
            // Q/K: swapped -> lane owns row m, registers own 4 consecutive cols
            #pragma unroll
            for (int kk = 0; kk < 6; ++kk) {
                half8 a0 = *(const half8*)(asb + rowb + ((cb + kk * 64) ^ sx));
                #pragma unroll
                for (int nt = 0; nt < 4; ++nt)
                    acc[nt] = mfma16(breg[kk][nt], a0, acc[nt]);
            }
            const int m  = mb * 64 + wave * 16 + l16;
            const int b_ = (int)((unsigned)m / 98u);
            const int i  = m - b_ * 98;
            const size_t bsbase = (size_t)(b_ * 2 + s) * NH;
            #pragma unroll
            for (int nt = 0; nt < 4; ++nt) {
                int rm = nbr * 64 + nt * 16 + quad * 4;
                int hh = rm >> 5, d0 = rm & 31;
                half4 hv = { (_Float16)(acc[nt][0] + biasq[nt].x),
                             (_Float16)(acc[nt][1] + biasq[nt].y),
                             (_Float16)(acc[nt][2] + biasq[nt].z),
                             (_Float16)(acc[nt][3] + biasq[nt].w) };
                *(half4*)(qk + (bsbase + hh) * HEADBLK + i * HD + d0) = hv;
            }
        }
        asm volatile("" ::: "memory");
        __builtin_amdgcn_s_barrier();      // protect buf before t+2 staging overwrites
        asm volatile("" ::: "memory");
    }
}

// ---------------- K2: attention, swapped QK^T, zero barriers ----------------
__global__ __launch_bounds__(448, 6) void wa_k2_attn(
    const _Float16* __restrict__ qk, const _Float16* __restrict__ vtg,
    const float* __restrict__ bm, _Float16* __restrict__ ao)
{
    const int h = blockIdx.x;           // 0..5
    const int b = blockIdx.y;           // 0..2047
    const int w = b & (NWIN - 1);
    const _Float16* qp = qk + ((size_t)(b * 2 + 0) * NH + h) * HEADBLK;
    const _Float16* kp = qk + ((size_t)(b * 2 + 1) * NH + h) * HEADBLK;
    const _Float16* vtp = vtg + (size_t)h * 32 * MM + (size_t)b * NN;   // row d: +d*MM

    __shared__ __align__(16) _Float16 P[112 * 136];   // unnormalized probs, wave-private rows

    const int tid  = threadIdx.x;
    const int lane = tid & 63, wave = tid >> 6;
    const int l16  = lane & 15, quad = lane >> 4;

    const int qrow = wave * 16 + l16;               // 0..111
    const int qrc  = qrow < NN ? qrow : NN - 1;     // clamp pad rows

    const float scale2 = 0.17677669529663687f * 1.4426950408889634f;  // hd^-0.5 * log2e

    half8 bq = *(const half8*)(qp + qrc * HD + quad * 8);             // Q as B-operand
    const float* bmrow = bm + ((size_t)(w * NH + h) * NN + qrc) * 128;

    // S^T: 7 key tiles; garbage keys >= 98 killed by bm = -1e30
    f32x4 s[7];
    #pragma unroll
    for (int jt = 0; jt < 7; ++jt) {
        half8 ak = *(const half8*)(kp + (jt * 16 + l16) * HD + quad * 8);
        f32x4 z = {};
        s[jt] = mfma16(ak, bq, z);
    }
    #pragma unroll
    for (int jt = 0; jt < 7; ++jt) {
        float4 bmv = *(const float4*)(bmrow + jt * 16 + quad * 4);
        s[jt][0] = fmaf(s[jt][0], scale2, bmv.x);
        s[jt][1] = fmaf(s[jt][1], scale2, bmv.y);
        s[jt][2] = fmaf(s[jt][2], scale2, bmv.z);
        s[jt][3] = fmaf(s[jt][3], scale2, bmv.w);
    }

    // row max: vector tree, then 2 cross-half shuffles
    f32x4 vm = s[0];
    #pragma unroll
    for (int jt = 1; jt < 7; ++jt) {
        vm[0] = fmaxf(vm[0], s[jt][0]); vm[1] = fmaxf(vm[1], s[jt][1]);
        vm[2] = fmaxf(vm[2], s[jt][2]); vm[3] = fmaxf(vm[3], s[jt][3]);
    }
    float mx = fmaxf(fmaxf(vm[0], vm[1]), fmaxf(vm[2], vm[3]));
    mx = fmaxf(mx, __shfl_xor(mx, 16));
    mx = fmaxf(mx, __shfl_xor(mx, 32));

    // exp2, vector-tree sum, 2 shuffles
    f32x4 vs = {};
    #pragma unroll
    for (int jt = 0; jt < 7; ++jt) {
        #pragma unroll
        for (int rr = 0; rr < 4; ++rr) {
            float p = __builtin_amdgcn_exp2f(s[jt][rr] - mx);
            s[jt][rr] = p;
            vs[rr] += p;
        }
    }
    float sum = (vs[0] + vs[1]) + (vs[2] + vs[3]);
    sum += __shfl_xor(sum, 16);
    sum += __shfl_xor(sum, 32);
    float inv = __builtin_amdgcn_rcpf(sum);

    // write unnormalized P (own rows only): 7 packed b64 + zero-fill cols 112..127
    _Float16* prow = P + qrow * 136;
    #pragma unroll
    for (int jt = 0; jt < 7; ++jt) {
        half4 hv = { (_Float16)s[jt][0], (_Float16)s[jt][1],
                     (_Float16)s[jt][2], (_Float16)s[jt][3] };
        *(half4*)(prow + jt * 16 + quad * 4) = hv;
    }
    { half4 z4 = {}; *(half4*)(prow + 112 + quad * 4) = z4; }

    // per-output-row 1/sum via intra-wave shuffle
    float invr[4];
    #pragma unroll
    for (int rr = 0; rr < 4; ++rr) invr[rr] = __shfl(inv, quad * 4 + rr);

    // PV: A = own P rows (same-wave LDS, in-order), B = V^T rows from vtg
    half8 pa[4];
    #pragma unroll
    for (int kc = 0; kc < 4; ++kc)
        pa[kc] = *(const half8*)(P + qrow * 136 + kc * 32 + quad * 8);

    #pragma unroll
    for (int nt = 0; nt < 2; ++nt) {
        f32x4 acc = {};
        #pragma unroll
        for (int kc = 0; kc < 4; ++kc) {
            half8 vb = ((const half8u*)(vtp + (size_t)(nt * 16 + l16) * MM
                                        + kc * 32 + quad * 8))->v;
            acc = mfma16(pa[kc], vb, acc);
        }
        #pragma unroll
        for (int rr = 0; rr < 4; ++rr) {
            int i = wave * 16 + quad * 4 + rr;
            if (i < NN)
                ao[((size_t)b * NN + i) * CC + h * HD + nt * 16 + l16] =
                    (_Float16)(acc[rr] * invr[rr]);
        }
    }
}

// ---------------- K3: output projection (persistent depth-2, swapped, T=4) ----------------
// grid 2352 = 8 xcd * 3 nb * 98; chunk = 4 consecutive 64-row tiles of ao.
__global__ __launch_bounds__(256, 2) void wa_k3_proj(
    const _Float16* __restrict__ ao, const _Float16* __restrict__ w2,
    const float* __restrict__ o_b, float* __restrict__ out)
{
    const int id = blockIdx.x;               // 0..2351
    const int c8 = id & 7;
    const int r  = id >> 3;                  // 0..293 = 3*98
    const int nb = r % 3;
    const int chunk = c8 * 98 + r / 3;       // 0..783
    __shared__ __align__(128) _Float16 As[3][64 * 192];   // 3 x 24 KB

    const int tid  = threadIdx.x;
    const int lane = tid & 63, wave = tid >> 6;
    const int l16  = lane & 15, quad = lane >> 4;

    int soff[6];
    #pragma unroll
    for (int i = 0; i < 6; ++i) {
        int off = i * 4096 + wave * 1024 + lane * 16;
        int row = off / 384;
        int col = off - row * 384;
        soff[i] = row * 384 + (col ^ ((row & 7) << 4));
    }

    half8 breg[6][4];
    const _Float16* bbase = w2 + (size_t)(nb * 64 + l16) * CC + quad * 8;
    #pragma unroll
    for (int kk = 0; kk < 6; ++kk)
        #pragma unroll
        for (int nt = 0; nt < 4; ++nt)
            breg[kk][nt] = *(const half8*)(bbase + nt * 16 * CC + kk * 32);

    float4 ob4[4];
    #pragma unroll
    for (int nt = 0; nt < 4; ++nt)
        ob4[nt] = *(const float4*)(o_b + nb * 64 + nt * 16 + quad * 4);

    asm volatile("" ::: "memory");

    const char* xb0 = (const char*)ao + (size_t)chunk * 4 * TILE_BYTES;
    #pragma unroll
    for (int p = 0; p < 2; ++p) {
        char* dst = (char*)As[p] + wave * 1024;
        const char* src = xb0 + (size_t)p * TILE_BYTES;
        #pragma unroll
        for (int i = 0; i < 6; ++i)
            async_copy16(dst + i * 4096, src + soff[i]);
    }

    const int sx   = (l16 & 7) << 4;
    const int rowb = (wave * 16 + l16) * 384;
    const int cb   = quad * 16;

    #pragma unroll
    for (int t = 0; t < 4; ++t) {
        if (t < 2) {
            char* dst = (char*)As[(t + 2) % 3] + wave * 1024;
            const char* src = xb0 + (size_t)(t + 2) * TILE_BYTES;
            #pragma unroll
            for (int i = 0; i < 6; ++i)
                async_copy16(dst + i * 4096, src + soff[i]);
        }
        if (t == 0)      asm volatile("s_waitcnt vmcnt(12)" ::: "memory");
        else if (t == 1) asm volatile("s_waitcnt vmcnt(16)" ::: "memory");
        else if (t == 2) asm volatile("s_waitcnt vmcnt(14)" ::: "memory");
        else             asm volatile("s_waitcnt vmcnt(8)"  ::: "memory");
        __builtin_amdgcn_s_barrier();
        asm volatile("" ::: "memory");

        const char* asb = (const char*)As[t % 3];
        const int mb = chunk * 4 + t;
        f32x4 acc[4] = {};
        #pragma unroll
        for (int kk = 0; kk < 6; ++kk) {
            half8 a0 = *(const half8*)(asb + rowb + ((cb + kk * 64) ^ sx));
            #pragma unroll
            for (int nt = 0; nt < 4; ++nt)
                acc[nt] = mfma16(breg[kk][nt], a0, acc[nt]);   // swapped: lane owns row m
        }

        const int m = mb * 64 + wave * 16 + l16;
        float* orow = out + (size_t)m * CC + nb * 64 + quad * 4;
        #pragma unroll
        for (int nt = 0; nt < 4; ++nt) {
            float4 o = { acc[nt][0] + ob4[nt].x, acc[nt][1] + ob4[nt].y,
                         acc[nt][2] + ob4[nt].z, acc[nt][3] + ob4[nt].w };
            *(float4*)(orow + nt * 16) = o;
        }
        asm volatile("" ::: "memory");
        __builtin_amdgcn_s_barrier();
        asm volatile("" ::: "memory");
    }
}

// ---------------- launcher ----------------
extern "C" void kernel_launch(void* const* d_in, const int* in_sizes, int n_in,
                              void* d_out, int out_size, void* d_ws, size_t ws_size,
                              hipStream_t stream)
{
    const float* x          = (const float*)d_in[0];
    const float* mask       = (const float*)d_in[1];
    const float* qkv_w      = (const float*)d_in[2];
    const float* qkv_b      = (const float*)d_in[3];
    const float* o_w        = (const float*)d_in[4];
    const float* o_b        = (const float*)d_in[5];
    const float* bias_table = (const float*)d_in[6];
    const int*   rel_index  = (const int*)d_in[7];

    char* ws = (char*)d_ws;
    _Float16* qk  = (_Float16*)(ws + WS_QK);
    _Float16* vtg = (_Float16*)(ws + WS_VT);
    _Float16* ao  = (_Float16*)(ws + WS_AO);
    _Float16* wqh = (_Float16*)(ws + WS_AO);    // alias: consumed by K1 before K2 writes ao
    _Float16* w2  = (_Float16*)(ws + WS_W2);
    float*    out = (float*)d_out;
    _Float16* xh  = (_Float16*)d_out;                       // K0 writes, K1 reads
    float*    bm  = (float*)((char*)d_out + XH_BYTES);      // K0 writes, K2 reads; K3 overwrites

    wa_k0_prep<<<2048, 256, 0, stream>>>(
        x, o_w, qkv_w, bias_table, rel_index, mask, w2, wqh, bm, xh);
    wa_k1_qkv<<<3528, 256, 0, stream>>>(xh, wqh, qkv_b, qk, vtg);
    wa_k2_attn<<<dim3(NH, NB), 448, 0, stream>>>(qk, vtg, bm, ao);
    wa_k3_proj<<<2352, 256, 0, stream>>>(ao, w2, o_b, out);
}